// Round 2
// baseline (182.305 us; speedup 1.0000x reference)
//
#include <hip/hip_runtime.h>
#include <hip/hip_bf16.h>

#define NN 50000
#define NE 800000
#define DIM 128

typedef float f32x4 __attribute__((ext_vector_type(4)));
typedef __bf16 bf16x8 __attribute__((ext_vector_type(8)));

// K0: V[d][k] (k<128 -> Wg[d][k], else Wg+Wl), bf16, row stride 256
__global__ void build_v(const float* __restrict__ Wg, const float* __restrict__ Wl,
                        __bf16* __restrict__ V) {
    int i = blockIdx.x * blockDim.x + threadIdx.x;
    if (i >= DIM * 256) return;
    int d = i >> 8;
    int k = i & 255;
    float v;
    if (k < DIM) v = Wg[d * DIM + k];
    else         v = Wg[d * DIM + (k - DIM)] + Wl[d * DIM + (k - DIM)];
    V[i] = (__bf16)v;
}

// K1: off[n] = lower_bound(seg, n), n in [0, NN]
__global__ void build_off(const int* __restrict__ seg, int* __restrict__ off) {
    int n = blockIdx.x * blockDim.x + threadIdx.x;
    if (n > NN) return;
    int lo = 0, hi = NE;
    while (lo < hi) {
        int mid = (lo + hi) >> 1;
        if (seg[mid] < n) lo = mid + 1; else hi = mid;
    }
    off[n] = lo;
}

// K2: per-node mean of gathered neighbor rows -> bf16; count -> cnt_ws
__global__ void __launch_bounds__(128) seg_mean(const float* __restrict__ x,
        const int* __restrict__ nidx, const int* __restrict__ off,
        int* __restrict__ cnt_ws, __bf16* __restrict__ meanb) {
    int n = blockIdx.x;
    int t = threadIdx.x;
    int s = off[n], e = off[n + 1];
    float sum = 0.f;
    int i = s;
    for (; i + 2 <= e; i += 2) {
        int i0 = nidx[i], i1 = nidx[i + 1];
        float a = x[i0 * DIM + t];
        float b = x[i1 * DIM + t];
        sum += a + b;
    }
    if (i < e) sum += x[nidx[i] * DIM + t];
    int c = e - s;
    float mean = c > 0 ? sum / (float)c : 0.f;
    meanb[n * DIM + t] = (__bf16)mean;
    if (t == 0) cnt_ws[n] = c;
}

// K3: one wave computes 16 nodes x 128 out dims, K=256 (x fp32 part + mean bf16 part)
__global__ void __launch_bounds__(64) gemm_ep(const float* __restrict__ x,
        const __bf16* __restrict__ meanb, const __bf16* __restrict__ V,
        const float* __restrict__ bias, const int* __restrict__ cnt_ws,
        float* __restrict__ out) {
    int m0 = blockIdx.x * 16;
    int lane = threadIdx.x;
    int rowin = lane & 15;
    int kg = lane >> 4;      // 0..3
    int row = m0 + rowin;

    f32x4 acc[8] = {};

    // K steps 0..3: A-frag from x (fp32 -> bf16 in-register); k = s*32 + kg*8 + j
    #pragma unroll
    for (int s = 0; s < 4; ++s) {
        int k0 = s * 32 + kg * 8;
        const float* xp = x + row * DIM + k0;
        f32x4 v0 = *reinterpret_cast<const f32x4*>(xp);
        f32x4 v1 = *reinterpret_cast<const f32x4*>(xp + 4);
        bf16x8 a;
        a[0]=(__bf16)v0[0]; a[1]=(__bf16)v0[1]; a[2]=(__bf16)v0[2]; a[3]=(__bf16)v0[3];
        a[4]=(__bf16)v1[0]; a[5]=(__bf16)v1[1]; a[6]=(__bf16)v1[2]; a[7]=(__bf16)v1[3];
        #pragma unroll
        for (int f = 0; f < 8; ++f) {
            int d = f * 16 + rowin;
            bf16x8 b = *reinterpret_cast<const bf16x8*>(&V[d * 256 + k0]);
            acc[f] = __builtin_amdgcn_mfma_f32_16x16x32_bf16(a, b, acc[f], 0, 0, 0);
        }
    }
    // K steps 4..7: A-frag from meanb (bf16), V columns 128..255
    #pragma unroll
    for (int s = 0; s < 4; ++s) {
        int k0 = s * 32 + kg * 8;
        bf16x8 a = *reinterpret_cast<const bf16x8*>(&meanb[row * DIM + k0]);
        #pragma unroll
        for (int f = 0; f < 8; ++f) {
            int d = f * 16 + rowin;
            bf16x8 b = *reinterpret_cast<const bf16x8*>(&V[d * 256 + 128 + k0]);
            acc[f] = __builtin_amdgcn_mfma_f32_16x16x32_bf16(a, b, acc[f], 0, 0, 0);
        }
    }

    // epilogue: C/D layout col = lane&15, row = (lane>>4)*4 + r  [m89-verified]
    int colin = lane & 15;
    int rbase = (lane >> 4) * 4;
    int cz[4];
    #pragma unroll
    for (int r = 0; r < 4; ++r) cz[r] = cnt_ws[m0 + rbase + r];
    #pragma unroll
    for (int f = 0; f < 8; ++f) {
        int d = f * 16 + colin;
        float bs = bias[d];
        #pragma unroll
        for (int r = 0; r < 4; ++r) {
            int n = m0 + rbase + r;
            float v = acc[f][r];
            float z = v + (cz[r] == 0 ? v : 0.f) + bs;  // deg==0 -> 2*global_maps
            out[n * DIM + d] = z > 0.f ? z : expm1f(z); // ELU(alpha=1)
        }
    }
}

extern "C" void kernel_launch(void* const* d_in, const int* in_sizes, int n_in,
                              void* d_out, int out_size, void* d_ws, size_t ws_size,
                              hipStream_t stream) {
    const float* x    = (const float*)d_in[0];
    const float* Wg   = (const float*)d_in[1];
    const float* Wl   = (const float*)d_in[2];
    const float* bias = (const float*)d_in[3];
    const int*   nidx = (const int*)d_in[4];
    const int*   seg  = (const int*)d_in[5];
    float* out = (float*)d_out;

    char* p = (char*)d_ws;
    __bf16* V = (__bf16*)p;       p += DIM * 256 * 2;                      // 64 KB
    int* off = (int*)p;           p += (((NN + 1) * 4) + 511) & ~511ull;   // lower_bound offsets
    int* cnt = (int*)p;           p += ((NN * 4) + 511) & ~511ull;
    __bf16* meanb = (__bf16*)p;   // NN*128 bf16 = 12.8 MB

    build_v  <<<(DIM * 256 + 255) / 256, 256, 0, stream>>>(Wg, Wl, V);
    build_off<<<(NN + 1 + 255) / 256,   256, 0, stream>>>(seg, off);
    seg_mean <<<NN, 128, 0, stream>>>(x, nidx, off, cnt, meanb);
    gemm_ep  <<<NN / 16, 64, 0, stream>>>(x, meanb, V, bias, cnt, out);
}

// Round 4
// 155.743 us; speedup vs baseline: 1.1705x; 1.1705x over previous
//
#include <hip/hip_runtime.h>
#include <hip/hip_bf16.h>

#define NN 50000
#define NE 800000
#define DIM 128
#define NTILES (NN / 16)
#define GEMM_BLOCKS 784

typedef float f32x4 __attribute__((ext_vector_type(4)));
typedef __bf16 bf16x8 __attribute__((ext_vector_type(8)));

static __device__ __forceinline__ float bflo(unsigned v) {
    unsigned b = v << 16; return __builtin_bit_cast(float, b);
}
static __device__ __forceinline__ float bfhi(unsigned v) {
    unsigned b = v & 0xffff0000u; return __builtin_bit_cast(float, b);
}
static __device__ __forceinline__ unsigned short bfbits(float f) {
    __bf16 b = (__bf16)f; return __builtin_bit_cast(unsigned short, b);
}

// K0: V[d][k] (k<128 -> Wg[d][k], else Wg+Wl), bf16, row stride 256
__global__ void build_v(const float* __restrict__ Wg, const float* __restrict__ Wl,
                        __bf16* __restrict__ V) {
    int i = blockIdx.x * blockDim.x + threadIdx.x;
    if (i >= DIM * 256) return;
    int d = i >> 8;
    int k = i & 255;
    float v;
    if (k < DIM) v = Wg[d * DIM + k];
    else         v = Wg[d * DIM + (k - DIM)] + Wl[d * DIM + (k - DIM)];
    V[i] = (__bf16)v;
}

// K0b: x (fp32) -> xb (bf16), 8 elems/thread
__global__ void xb_conv(const float* __restrict__ x, __bf16* __restrict__ xb) {
    int i = blockIdx.x * blockDim.x + threadIdx.x;   // 800000 threads
    const float* p = x + i * 8;
    f32x4 v0 = *reinterpret_cast<const f32x4*>(p);
    f32x4 v1 = *reinterpret_cast<const f32x4*>(p + 4);
    bf16x8 o;
    o[0]=(__bf16)v0[0]; o[1]=(__bf16)v0[1]; o[2]=(__bf16)v0[2]; o[3]=(__bf16)v0[3];
    o[4]=(__bf16)v1[0]; o[5]=(__bf16)v1[1]; o[6]=(__bf16)v1[2]; o[7]=(__bf16)v1[3];
    *reinterpret_cast<bf16x8*>(xb + i * 8) = o;
}

// K1: off[n] = lower_bound(seg, n), n in [0, NN]
__global__ void build_off(const int* __restrict__ seg, int* __restrict__ off) {
    int n = blockIdx.x * blockDim.x + threadIdx.x;
    if (n > NN) return;
    int lo = 0, hi = NE;
    while (lo < hi) {
        int mid = (lo + hi) >> 1;
        if (seg[mid] < n) lo = mid + 1; else hi = mid;
    }
    off[n] = lo;
}

// K2: one wave per node; gather bf16 rows, mean in fp32, store bf16
__global__ void __launch_bounds__(256) seg_mean(const __bf16* __restrict__ xb,
        const int* __restrict__ nidx, const int* __restrict__ off,
        int* __restrict__ cnt_ws, __bf16* __restrict__ meanb) {
    int n = blockIdx.x * 4 + (threadIdx.x >> 6);
    if (n >= NN) return;
    int lane = threadIdx.x & 63;
    int s = off[n], e = off[n + 1];
    const unsigned* xu = reinterpret_cast<const unsigned*>(xb);
    float s0 = 0.f, s1 = 0.f;
    int i = s;
    for (; i + 4 <= e; i += 4) {
        int i0 = nidx[i], i1 = nidx[i+1], i2 = nidx[i+2], i3 = nidx[i+3];
        unsigned v0 = xu[i0 * 64 + lane];
        unsigned v1 = xu[i1 * 64 + lane];
        unsigned v2 = xu[i2 * 64 + lane];
        unsigned v3 = xu[i3 * 64 + lane];
        s0 += bflo(v0) + bflo(v1) + bflo(v2) + bflo(v3);
        s1 += bfhi(v0) + bfhi(v1) + bfhi(v2) + bfhi(v3);
    }
    for (; i < e; ++i) {
        unsigned v = xu[nidx[i] * 64 + lane];
        s0 += bflo(v);
        s1 += bfhi(v);
    }
    int c = e - s;
    float inv = c > 0 ? 1.f / (float)c : 0.f;
    unsigned o = (unsigned)bfbits(s0 * inv) | ((unsigned)bfbits(s1 * inv) << 16);
    reinterpret_cast<unsigned*>(meanb)[n * 64 + lane] = o;
    if (lane == 0) cnt_ws[n] = c;
}

// K3: 4 waves/block; wave w owns output dims [w*32, w*32+32) with B resident
// in registers; grid-strides over 16-row tiles. K=256 (xb part + mean part).
__global__ void __launch_bounds__(256) gemm_ep(const __bf16* __restrict__ xb,
        const __bf16* __restrict__ meanb, const __bf16* __restrict__ V,
        const float* __restrict__ bias, const int* __restrict__ cnt_ws,
        float* __restrict__ out) {
    int tid = threadIdx.x;
    int w = tid >> 6;          // wave -> f-pair
    int lane = tid & 63;
    int rowin = lane & 15;     // A-row / C-col within fragment
    int kg = lane >> 4;        // k-group 0..3
    int rbase = kg * 4;

    // Preload B fragments: 8 K-steps x 2 f-tiles, register-resident
    bf16x8 Bf[8][2];
    #pragma unroll
    for (int s = 0; s < 8; ++s)
        #pragma unroll
        for (int ff = 0; ff < 2; ++ff) {
            int d = (w * 2 + ff) * 16 + rowin;
            Bf[s][ff] = *reinterpret_cast<const bf16x8*>(&V[d * 256 + s * 32 + kg * 8]);
        }
    float bs0 = bias[(w * 2) * 16 + rowin];
    float bs1 = bias[(w * 2 + 1) * 16 + rowin];

    for (int t = blockIdx.x; t < NTILES; t += gridDim.x) {
        int m0 = t * 16;
        int row = m0 + rowin;
        f32x4 acc0 = {}, acc1 = {};
        #pragma unroll
        for (int s = 0; s < 4; ++s) {
            bf16x8 a = *reinterpret_cast<const bf16x8*>(&xb[row * DIM + s * 32 + kg * 8]);
            acc0 = __builtin_amdgcn_mfma_f32_16x16x32_bf16(a, Bf[s][0], acc0, 0, 0, 0);
            acc1 = __builtin_amdgcn_mfma_f32_16x16x32_bf16(a, Bf[s][1], acc1, 0, 0, 0);
        }
        #pragma unroll
        for (int s = 0; s < 4; ++s) {
            bf16x8 a = *reinterpret_cast<const bf16x8*>(&meanb[row * DIM + s * 32 + kg * 8]);
            acc0 = __builtin_amdgcn_mfma_f32_16x16x32_bf16(a, Bf[s + 4][0], acc0, 0, 0, 0);
            acc1 = __builtin_amdgcn_mfma_f32_16x16x32_bf16(a, Bf[s + 4][1], acc1, 0, 0, 0);
        }
        // epilogue: C/D col = lane&15, row = (lane>>4)*4 + r
        #pragma unroll
        for (int r = 0; r < 4; ++r) {
            int n = m0 + rbase + r;
            int c = cnt_ws[n];
            float v0 = acc0[r];
            float z0 = v0 + (c == 0 ? v0 : 0.f) + bs0;
            out[n * DIM + (w * 2) * 16 + rowin] = z0 > 0.f ? z0 : expm1f(z0);
            float v1 = acc1[r];
            float z1 = v1 + (c == 0 ? v1 : 0.f) + bs1;
            out[n * DIM + (w * 2 + 1) * 16 + rowin] = z1 > 0.f ? z1 : expm1f(z1);
        }
    }
}

extern "C" void kernel_launch(void* const* d_in, const int* in_sizes, int n_in,
                              void* d_out, int out_size, void* d_ws, size_t ws_size,
                              hipStream_t stream) {
    const float* x    = (const float*)d_in[0];
    const float* Wg   = (const float*)d_in[1];
    const float* Wl   = (const float*)d_in[2];
    const float* bias = (const float*)d_in[3];
    const int*   nidx = (const int*)d_in[4];
    const int*   seg  = (const int*)d_in[5];
    float* out = (float*)d_out;

    char* p = (char*)d_ws;
    __bf16* V = (__bf16*)p;       p += DIM * 256 * 2;                      // 64 KB
    int* off = (int*)p;           p += (((NN + 1) * 4) + 511) & ~511ull;
    int* cnt = (int*)p;           p += ((NN * 4) + 511) & ~511ull;
    __bf16* meanb = (__bf16*)p;   p += (size_t)NN * DIM * 2;               // 12.8 MB
    __bf16* xb = (__bf16*)p;      // 12.8 MB

    build_v  <<<(DIM * 256 + 255) / 256, 256, 0, stream>>>(Wg, Wl, V);
    xb_conv  <<<(NN * DIM / 8) / 256, 256, 0, stream>>>(x, xb);
    build_off<<<(NN + 1 + 255) / 256, 256, 0, stream>>>(seg, off);
    seg_mean <<<(NN + 3) / 4, 256, 0, stream>>>(xb, nidx, off, cnt, meanb);
    gemm_ep  <<<GEMM_BLOCKS, 256, 0, stream>>>(xb, meanb, V, bias, cnt, out);
}